// Round 6
// baseline (654.507 us; speedup 1.0000x reference)
//
#include <hip/hip_runtime.h>
#include <math.h>

#define BB 32
#define CC 256
#define NPIX 1024     // 32*32
#define KD 16
#define NHEADS 4
#define VDIM 64
#define RR 23
#define PADR 11
#define EPSBN 1e-5f

typedef short short8v __attribute__((ext_vector_type(8)));
typedef short short4v __attribute__((ext_vector_type(4)));
typedef float floatx4 __attribute__((ext_vector_type(4)));

__device__ __forceinline__ unsigned short f2bf(float f) {
  union { float f; unsigned u; } c; c.f = f;
  unsigned u = c.u;
  return (unsigned short)((u + 0x7FFFu + ((u >> 16) & 1u)) >> 16);
}
__device__ __forceinline__ float bf2f(unsigned short h) {
  union { unsigned u; float f; } c; c.u = ((unsigned)h) << 16;
  return c.f;
}

// ---------------- K0: emb -> bf16 A-operand layout in global ----------------
__global__ __launch_bounds__(256) void k_emb(const float* __restrict__ emb,
    unsigned short* __restrict__ embA) {
  int l = blockIdx.x * 256 + threadIdx.x;
  if (l >= 23 * 16 * 32) return;
  int dr = l >> 9, rem = l & 511;
  int m = rem >> 5, kd = rem & 31;
  unsigned short val = 0;
  if (kd < 23) val = f2bf(emb[(size_t)m * 529 + dr * 23 + kd]);
  embA[l] = val;
}

// ---------------- K1: fused 144-channel 1x1-conv (GEMM) ----------------
__global__ __launch_bounds__(256) void k_proj(const float* __restrict__ x,
    const float* __restrict__ Wq, const float* __restrict__ Wk, const float* __restrict__ Wv,
    float* __restrict__ q_pre, float* __restrict__ k_pre, float* __restrict__ v_pre) {
  __shared__ float wlds[144 * 64];
  int b = blockIdx.y;
  int n = blockIdx.x * 32 + (threadIdx.x & 31);
  int og = threadIdx.x >> 5;   // 0..7
  float acc[18];
#pragma unroll
  for (int j = 0; j < 18; ++j) acc[j] = 0.f;
  for (int c0 = 0; c0 < CC; c0 += 64) {
    __syncthreads();
    for (int idx = threadIdx.x; idx < 144 * 64; idx += 256) {
      int row = idx >> 6, cc = idx & 63;
      const float* src = (row < 64) ? (Wq + (size_t)row * CC)
                        : (row < 80) ? (Wk + (size_t)(row - 64) * CC)
                                     : (Wv + (size_t)(row - 80) * CC);
      wlds[idx] = src[c0 + cc];
    }
    __syncthreads();
    for (int cs = 0; cs < 64; cs += 4) {
      float x0 = x[((size_t)b * CC + c0 + cs + 0) * NPIX + n];
      float x1 = x[((size_t)b * CC + c0 + cs + 1) * NPIX + n];
      float x2 = x[((size_t)b * CC + c0 + cs + 2) * NPIX + n];
      float x3 = x[((size_t)b * CC + c0 + cs + 3) * NPIX + n];
#pragma unroll
      for (int j = 0; j < 18; ++j) {
        int o = og * 18 + j;
        const float4 w = *(const float4*)&wlds[o * 64 + cs];
        acc[j] = fmaf(x0, w.x, fmaf(x1, w.y, fmaf(x2, w.z, fmaf(x3, w.w, acc[j]))));
      }
    }
  }
#pragma unroll
  for (int j = 0; j < 18; ++j) {
    int o = og * 18 + j;
    if (o < 64)      q_pre[((size_t)b * 64 + o) * NPIX + n] = acc[j];
    else if (o < 80) k_pre[((size_t)b * 16 + (o - 64)) * NPIX + n] = acc[j];
    else             v_pre[((size_t)b * 64 + (o - 80)) * NPIX + n] = acc[j];
  }
}

// ---------------- K2a: BN batch stats -> scale/shift ----------------
__global__ __launch_bounds__(256) void k_bnstats(const float* __restrict__ q_pre,
    const float* __restrict__ v_pre,
    const float* __restrict__ bn_q_w, const float* __restrict__ bn_q_b,
    const float* __restrict__ bn_v_w, const float* __restrict__ bn_v_b,
    float* __restrict__ stats) {
  int ch = blockIdx.x;            // 0..127
  bool isq = ch < 64;
  int c = isq ? ch : ch - 64;
  const float* src = (isq ? q_pre : v_pre) + (size_t)c * NPIX;
  float s = 0.f, ss = 0.f;
  for (int idx = threadIdx.x; idx < BB * NPIX; idx += 256) {
    int bb = idx >> 10, nn = idx & 1023;
    float v = src[(size_t)bb * 64 * NPIX + nn];
    s += v; ss = fmaf(v, v, ss);
  }
#pragma unroll
  for (int off = 32; off > 0; off >>= 1) {
    s += __shfl_down(s, off);
    ss += __shfl_down(ss, off);
  }
  __shared__ float sh[8];
  if ((threadIdx.x & 63) == 0) {
    sh[(threadIdx.x >> 6) * 2] = s;
    sh[(threadIdx.x >> 6) * 2 + 1] = ss;
  }
  __syncthreads();
  if (threadIdx.x == 0) {
    s = sh[0] + sh[2] + sh[4] + sh[6];
    ss = sh[1] + sh[3] + sh[5] + sh[7];
    const float inv = 1.0f / (float)(BB * NPIX);
    float mean = s * inv;
    float var = ss * inv - mean * mean;
    float rstd = rsqrtf(var + EPSBN);
    float w = isq ? bn_q_w[c] : bn_v_w[c];
    float bi = isq ? bn_q_b[c] : bn_v_b[c];
    float scale = rstd * w;
    float shift = bi - mean * scale;
    if (isq) { stats[c] = scale; stats[64 + c] = shift; }
    else     { stats[128 + c] = scale; stats[192 + c] = shift; }
  }
}

// ---------------- K2c: normalize v in place + transposed copy ----------------
__global__ __launch_bounds__(256) void k_norm_v(float* __restrict__ vn,
    const float* __restrict__ stats, float* __restrict__ vnT) {
  __shared__ float lds[64 * 65];
  int b = blockIdx.y, n0 = blockIdx.x * 64;
  for (int l = threadIdx.x; l < 4096; l += 256) {
    int o = l >> 6, nn = l & 63;
    size_t a = ((size_t)b * 64 + o) * NPIX + n0 + nn;
    float v = fmaf(vn[a], stats[128 + o], stats[192 + o]);
    vn[a] = v;
    lds[o * 65 + nn] = v;
  }
  __syncthreads();
  for (int l = threadIdx.x; l < 4096; l += 256) {
    int nn = l >> 6, o = l & 63;
    vnT[((size_t)b * NPIX + n0 + nn) * 64 + o] = lds[o * 65 + nn];
  }
}

// ---------------- K3: softmax over N per (b,k) ----------------
__global__ __launch_bounds__(256) void k_softmax(const float* __restrict__ k_pre,
    float* __restrict__ p) {
  int b = blockIdx.y, k = blockIdx.x, t = threadIdx.x;
  const float* src = k_pre + ((size_t)b * 16 + k) * NPIX;
  float v[4];
  float mx = -1e30f;
#pragma unroll
  for (int i = 0; i < 4; ++i) { v[i] = src[t + 256 * i]; mx = fmaxf(mx, v[i]); }
#pragma unroll
  for (int off = 32; off > 0; off >>= 1) mx = fmaxf(mx, __shfl_down(mx, off));
  __shared__ float shm[4], shs[4];
  if ((t & 63) == 0) shm[t >> 6] = mx;
  __syncthreads();
  mx = fmaxf(fmaxf(shm[0], shm[1]), fmaxf(shm[2], shm[3]));
  float s = 0.f;
#pragma unroll
  for (int i = 0; i < 4; ++i) { v[i] = __expf(v[i] - mx); s += v[i]; }
#pragma unroll
  for (int off = 32; off > 0; off >>= 1) s += __shfl_down(s, off);
  if ((t & 63) == 0) shs[t >> 6] = s;
  __syncthreads();
  float r = 1.0f / (shs[0] + shs[1] + shs[2] + shs[3]);
  float* dst = p + ((size_t)b * 16 + k) * NPIX;
#pragma unroll
  for (int i = 0; i < 4; ++i) dst[t + 256 * i] = v[i] * r;
}

// ---------------- K4: lambda_c[b][k][v] ----------------
__global__ __launch_bounds__(256) void k_lambda_c(const float* __restrict__ p,
    const float* __restrict__ vnT, float* __restrict__ lc) {
  __shared__ float pl[1024];
  __shared__ float red[256];
  int b = blockIdx.y, k = blockIdx.x, t = threadIdx.x;
  const float* ps = p + ((size_t)b * 16 + k) * NPIX;
  for (int l = t; l < 1024; l += 256) pl[l] = ps[l];
  __syncthreads();
  int v = t & 63, nq = t >> 6;
  const float* vt = vnT + (size_t)b * NPIX * 64;
  float acc = 0.f;
  for (int n = nq * 256; n < nq * 256 + 256; ++n)
    acc = fmaf(pl[n], vt[(size_t)n * 64 + v], acc);
  red[t] = acc;
  __syncthreads();
  if (t < 64)
    lc[((size_t)b * 16 + k) * 64 + t] = red[t] + red[64 + t] + red[128 + t] + red[192 + t];
}

// ---------------- shared LDS layout for conv kernels ----------------
#define IMG_RS 68            // shorts per padded row
#define IMG_CS (54 * IMG_RS) // shorts per copy = 3672
#define LAM_RS 1032          // lambda row stride in shorts (1024 + 8 pad)

union KMainLDS {
  short imgc[4 * IMG_CS];   // 29376 B
  short lam[16 * LAM_RS];   // 33024 B
};

// ---------------- K5a: MFMA conv -> lamG (R4 conv, epilogue removed) ---------
__global__ __launch_bounds__(256, 3) void k_conv(const float* __restrict__ vn,
    const float* __restrict__ lc, const unsigned short* __restrict__ embA,
    unsigned short* __restrict__ lamG) {
  __shared__ __align__(16) KMainLDS u;
  __shared__ float lcv[16];
  int b = blockIdx.y, v = blockIdx.x, t = threadIdx.x;

  int4* z4 = (int4*)u.imgc;
  for (int l = t; l < 1836; l += 256) z4[l] = make_int4(0, 0, 0, 0);
  if (t < 16) lcv[t] = lc[((size_t)b * 16 + t) * 64 + v];
  __syncthreads();

  const float* vsrc = vn + ((size_t)b * 64 + v) * NPIX;
  for (int l = t; l < 512; l += 256) {
    int pix = l * 2;
    int y = pix >> 5, xx = pix & 31;
    float2 vv = *(const float2*)(vsrc + pix);
    unsigned short h0 = f2bf(vv.x), h1 = f2bf(vv.y);
#pragma unroll
    for (int s = 0; s < 4; ++s) {
      int base = s * IMG_CS + (y + PADR) * IMG_RS + xx + PADR + s;
      u.imgc[base] = (short)h0;
      u.imgc[base + 1] = (short)h1;
    }
  }
  __syncthreads();

  int lane = t & 63, wv = t >> 6;
  int nl = lane & 15, quad = lane >> 4;
  int y0 = wv * 8;
  int scopy = (4 - (nl & 3)) & 3;
  int colbase = scopy * IMG_CS + nl + quad * 8 + scopy;
  const unsigned short* aptr = embA + nl * 32 + quad * 8;

  floatx4 acc[16];
#pragma unroll
  for (int i = 0; i < 16; ++i) acc[i] = (floatx4){0.f, 0.f, 0.f, 0.f};

  short8v afrag = *(const short8v*)aptr;
  for (int dr = 0; dr < RR; ++dr) {
    short8v anext = afrag;
    if (dr < RR - 1) anext = *(const short8v*)(aptr + (dr + 1) * 512);
    int rowoff = (y0 + dr) * IMG_RS + colbase;
#pragma unroll
    for (int tt = 0; tt < 16; ++tt) {
      int addr = rowoff + (tt >> 1) * IMG_RS + ((tt & 1) << 4);
      union { short8v s8; short4v s4[2]; } bu;
      bu.s4[0] = *(const short4v*)&u.imgc[addr];
      bu.s4[1] = *(const short4v*)&u.imgc[addr + 4];
      acc[tt] = __builtin_amdgcn_mfma_f32_16x16x32_bf16(afrag, bu.s8, acc[tt], 0, 0, 0);
    }
    afrag = anext;
  }

  __syncthreads();
#pragma unroll
  for (int tt = 0; tt < 16; ++tt) {
    int y = y0 + (tt >> 1), c0 = (tt & 1) << 4;
    int pix = y * 32 + c0 + nl;
#pragma unroll
    for (int r = 0; r < 4; ++r)
      u.lam[(quad * 4 + r) * LAM_RS + pix] = (short)f2bf(acc[tt][r] + lcv[quad * 4 + r]);
  }
  __syncthreads();

  // coalesced LDS -> global copy of lambda (16 rows x 1024 bf16 = 2048 uint4)
  uint4* dst = (uint4*)(lamG + ((size_t)(b * 64 + v)) * 16 * 1024);
  for (int idx = t; idx < 2048; idx += 256) {
    int row = idx >> 7, col = idx & 127;
    dst[row * 128 + col] = *(const uint4*)&u.lam[row * LAM_RS + col * 8];
  }
}

// ---------------- K5b: epilogue y = (1+g) * sum_k qn[k] * lambda[k] ----------
__global__ __launch_bounds__(256) void k_epi(const unsigned short* __restrict__ lamG,
    const float* __restrict__ q_pre, const float* __restrict__ stats,
    const float* __restrict__ gamma, float* __restrict__ out) {
  int b = blockIdx.y, v = blockIdx.x, t = threadIdx.x;
  int p0 = t * 4;
  const unsigned short* ls = lamG + ((size_t)(b * 64 + v)) * 16 * 1024;
  float yacc[4][4];
#pragma unroll
  for (int h = 0; h < 4; ++h)
#pragma unroll
    for (int i = 0; i < 4; ++i) yacc[h][i] = 0.f;
  const float* qb = q_pre + ((size_t)b * 64) * NPIX + p0;
#pragma unroll
  for (int k = 0; k < 16; ++k) {
    uint2 w = *(const uint2*)(ls + k * 1024 + p0);
    float l0 = bf2f((unsigned short)(w.x & 0xffffu));
    float l1 = bf2f((unsigned short)(w.x >> 16));
    float l2 = bf2f((unsigned short)(w.y & 0xffffu));
    float l3 = bf2f((unsigned short)(w.y >> 16));
#pragma unroll
    for (int h = 0; h < 4; ++h) {
      int o = h * 16 + k;
      float4 qv = *(const float4*)(qb + (size_t)o * NPIX);
      float s = stats[o], sh = stats[64 + o];
      yacc[h][0] = fmaf(fmaf(qv.x, s, sh), l0, yacc[h][0]);
      yacc[h][1] = fmaf(fmaf(qv.y, s, sh), l1, yacc[h][1]);
      yacc[h][2] = fmaf(fmaf(qv.z, s, sh), l2, yacc[h][2]);
      yacc[h][3] = fmaf(fmaf(qv.w, s, sh), l3, yacc[h][3]);
    }
  }
  float g1 = 1.0f + gamma[0];
#pragma unroll
  for (int h = 0; h < 4; ++h) {
    float4 r;
    r.x = g1 * yacc[h][0]; r.y = g1 * yacc[h][1];
    r.z = g1 * yacc[h][2]; r.w = g1 * yacc[h][3];
    *(float4*)&out[((size_t)b * 256 + h * 64 + v) * NPIX + p0] = r;
  }
}

// ---------------- K5 fallback: R4 fused k_main (verbatim, known-passing) -----
__global__ __launch_bounds__(256) void k_main(const float* __restrict__ vn,
    const float* __restrict__ q_pre, const float* __restrict__ stats,
    const float* __restrict__ lc, const unsigned short* __restrict__ embA,
    const float* __restrict__ gamma, float* __restrict__ out) {
  __shared__ __align__(16) KMainLDS u;
  __shared__ float lcv[16];
  int b = blockIdx.y, v = blockIdx.x, t = threadIdx.x;

  int4* z4 = (int4*)u.imgc;
  for (int l = t; l < 1836; l += 256) z4[l] = make_int4(0, 0, 0, 0);
  if (t < 16) lcv[t] = lc[((size_t)b * 16 + t) * 64 + v];
  __syncthreads();

  const float* vsrc = vn + ((size_t)b * 64 + v) * NPIX;
  for (int l = t; l < 512; l += 256) {
    int pix = l * 2;
    int y = pix >> 5, xx = pix & 31;
    float2 vv = *(const float2*)(vsrc + pix);
    unsigned short h0 = f2bf(vv.x), h1 = f2bf(vv.y);
#pragma unroll
    for (int s = 0; s < 4; ++s) {
      int base = s * IMG_CS + (y + PADR) * IMG_RS + xx + PADR + s;
      u.imgc[base] = (short)h0;
      u.imgc[base + 1] = (short)h1;
    }
  }
  __syncthreads();

  int lane = t & 63, wv = t >> 6;
  int nl = lane & 15, quad = lane >> 4;
  int y0 = wv * 8;
  int scopy = (4 - (nl & 3)) & 3;
  int colbase = scopy * IMG_CS + nl + quad * 8 + scopy;
  const unsigned short* aptr = embA + nl * 32 + quad * 8;

  floatx4 acc[16];
#pragma unroll
  for (int i = 0; i < 16; ++i) acc[i] = (floatx4){0.f, 0.f, 0.f, 0.f};

  short8v afrag = *(const short8v*)aptr;
  for (int dr = 0; dr < RR; ++dr) {
    short8v anext = afrag;
    if (dr < RR - 1) anext = *(const short8v*)(aptr + (dr + 1) * 512);
    int rowoff = (y0 + dr) * IMG_RS + colbase;
#pragma unroll
    for (int tt = 0; tt < 16; ++tt) {
      int addr = rowoff + (tt >> 1) * IMG_RS + ((tt & 1) << 4);
      union { short8v s8; short4v s4[2]; } bu;
      bu.s4[0] = *(const short4v*)&u.imgc[addr];
      bu.s4[1] = *(const short4v*)&u.imgc[addr + 4];
      acc[tt] = __builtin_amdgcn_mfma_f32_16x16x32_bf16(afrag, bu.s8, acc[tt], 0, 0, 0);
    }
    afrag = anext;
  }

  __syncthreads();
#pragma unroll
  for (int tt = 0; tt < 16; ++tt) {
    int y = y0 + (tt >> 1), c0 = (tt & 1) << 4;
    int pix = y * 32 + c0 + nl;
#pragma unroll
    for (int r = 0; r < 4; ++r)
      u.lam[(quad * 4 + r) * LAM_RS + pix] = (short)f2bf(acc[tt][r] + lcv[quad * 4 + r]);
  }
  __syncthreads();

  int p0 = t * 4;
  float yacc[4][4];
#pragma unroll
  for (int h = 0; h < 4; ++h)
#pragma unroll
    for (int i = 0; i < 4; ++i) yacc[h][i] = 0.f;
  const float* qb = q_pre + ((size_t)b * 64) * NPIX + p0;
#pragma unroll
  for (int k = 0; k < 16; ++k) {
    uint2 w = *(const uint2*)&u.lam[k * LAM_RS + p0];
    float l0 = bf2f((unsigned short)(w.x & 0xffffu));
    float l1 = bf2f((unsigned short)(w.x >> 16));
    float l2 = bf2f((unsigned short)(w.y & 0xffffu));
    float l3 = bf2f((unsigned short)(w.y >> 16));
#pragma unroll
    for (int h = 0; h < 4; ++h) {
      int o = h * 16 + k;
      float4 qv = *(const float4*)(qb + (size_t)o * NPIX);
      float s = stats[o], sh = stats[64 + o];
      yacc[h][0] = fmaf(fmaf(qv.x, s, sh), l0, yacc[h][0]);
      yacc[h][1] = fmaf(fmaf(qv.y, s, sh), l1, yacc[h][1]);
      yacc[h][2] = fmaf(fmaf(qv.z, s, sh), l2, yacc[h][2]);
      yacc[h][3] = fmaf(fmaf(qv.w, s, sh), l3, yacc[h][3]);
    }
  }
  float g1 = 1.0f + gamma[0];
#pragma unroll
  for (int h = 0; h < 4; ++h) {
    float4 r;
    r.x = g1 * yacc[h][0]; r.y = g1 * yacc[h][1];
    r.z = g1 * yacc[h][2]; r.w = g1 * yacc[h][3];
    *(float4*)&out[((size_t)b * 256 + h * 64 + v) * NPIX + p0] = r;
  }
}

extern "C" void kernel_launch(void* const* d_in, const int* in_sizes, int n_in,
                              void* d_out, int out_size, void* d_ws, size_t ws_size,
                              hipStream_t stream) {
  const float* x      = (const float*)d_in[0];
  const float* Wq     = (const float*)d_in[1];
  const float* bn_q_w = (const float*)d_in[2];
  const float* bn_q_b = (const float*)d_in[3];
  const float* Wk     = (const float*)d_in[4];
  const float* Wv     = (const float*)d_in[5];
  const float* bn_v_w = (const float*)d_in[6];
  const float* bn_v_b = (const float*)d_in[7];
  const float* emb    = (const float*)d_in[8];
  const float* gamma  = (const float*)d_in[9];
  float* out = (float*)d_out;

  float* ws    = (float*)d_ws;
  float* q_pre = ws;                                     // B*64*N
  float* k_pre = q_pre + (size_t)BB * 64 * NPIX;         // B*16*N
  float* vn    = k_pre + (size_t)BB * 16 * NPIX;         // B*64*N
  float* vnT   = vn    + (size_t)BB * 64 * NPIX;         // B*N*64
  float* p     = vnT   + (size_t)BB * NPIX * 64;         // B*16*N
  float* lc    = p     + (size_t)BB * 16 * NPIX;         // B*16*64
  float* stats = lc    + (size_t)BB * 16 * 64;           // 256
  unsigned short* embA = (unsigned short*)(stats + 256); // 23*16*32 ushorts
  unsigned short* lamG = embA + 23 * 16 * 32;            // B*64*16*N ushorts (64 MB)

  size_t need = ((size_t)(lamG - (unsigned short*)ws)) * 2
              + (size_t)BB * 64 * 16 * NPIX * 2;

  k_emb     <<<dim3(46),     256, 0, stream>>>(emb, embA);
  k_proj    <<<dim3(32, BB), 256, 0, stream>>>(x, Wq, Wk, Wv, q_pre, k_pre, vn);
  k_bnstats <<<dim3(128),    256, 0, stream>>>(q_pre, vn, bn_q_w, bn_q_b, bn_v_w, bn_v_b, stats);
  k_norm_v  <<<dim3(16, BB), 256, 0, stream>>>(vn, stats, vnT);
  k_softmax <<<dim3(16, BB), 256, 0, stream>>>(k_pre, p);
  k_lambda_c<<<dim3(16, BB), 256, 0, stream>>>(p, vnT, lc);
  if (ws_size >= need) {
    k_conv  <<<dim3(64, BB), 256, 0, stream>>>(vn, lc, embA, lamG);
    k_epi   <<<dim3(64, BB), 256, 0, stream>>>(lamG, q_pre, stats, gamma, out);
  } else {
    k_main  <<<dim3(64, BB), 256, 0, stream>>>(vn, q_pre, stats, lc, embA, gamma, out);
  }
}

// Round 7
// 362.445 us; speedup vs baseline: 1.8058x; 1.8058x over previous
//
#include <hip/hip_runtime.h>
#include <math.h>

#define BB 32
#define CC 256
#define NPIX 1024     // 32*32
#define KD 16
#define NHEADS 4
#define VDIM 64
#define RR 23
#define PADR 11
#define EPSBN 1e-5f

typedef short short8v __attribute__((ext_vector_type(8)));
typedef short short4v __attribute__((ext_vector_type(4)));
typedef float floatx4 __attribute__((ext_vector_type(4)));

__device__ __forceinline__ unsigned short f2bf(float f) {
  union { float f; unsigned u; } c; c.f = f;
  unsigned u = c.u;
  return (unsigned short)((u + 0x7FFFu + ((u >> 16) & 1u)) >> 16);
}
__device__ __forceinline__ float bf2f(unsigned short h) {
  union { unsigned u; float f; } c; c.u = ((unsigned)h) << 16;
  return c.f;
}

// ---------------- K0: emb -> bf16 A-operand layout in global ----------------
__global__ __launch_bounds__(256) void k_emb(const float* __restrict__ emb,
    unsigned short* __restrict__ embA) {
  int l = blockIdx.x * 256 + threadIdx.x;
  if (l >= 23 * 16 * 32) return;
  int dr = l >> 9, rem = l & 511;
  int m = rem >> 5, kd = rem & 31;
  unsigned short val = 0;
  if (kd < 23) val = f2bf(emb[(size_t)m * 529 + dr * 23 + kd]);
  embA[l] = val;
}

// ---------------- K1: fused 144-channel 1x1-conv (GEMM) ----------------
__global__ __launch_bounds__(256) void k_proj(const float* __restrict__ x,
    const float* __restrict__ Wq, const float* __restrict__ Wk, const float* __restrict__ Wv,
    float* __restrict__ q_pre, float* __restrict__ k_pre, float* __restrict__ v_pre) {
  __shared__ float wlds[144 * 64];
  int b = blockIdx.y;
  int n = blockIdx.x * 32 + (threadIdx.x & 31);
  int og = threadIdx.x >> 5;   // 0..7
  float acc[18];
#pragma unroll
  for (int j = 0; j < 18; ++j) acc[j] = 0.f;
  for (int c0 = 0; c0 < CC; c0 += 64) {
    __syncthreads();
    for (int idx = threadIdx.x; idx < 144 * 64; idx += 256) {
      int row = idx >> 6, cc = idx & 63;
      const float* src = (row < 64) ? (Wq + (size_t)row * CC)
                        : (row < 80) ? (Wk + (size_t)(row - 64) * CC)
                                     : (Wv + (size_t)(row - 80) * CC);
      wlds[idx] = src[c0 + cc];
    }
    __syncthreads();
    for (int cs = 0; cs < 64; cs += 4) {
      float x0 = x[((size_t)b * CC + c0 + cs + 0) * NPIX + n];
      float x1 = x[((size_t)b * CC + c0 + cs + 1) * NPIX + n];
      float x2 = x[((size_t)b * CC + c0 + cs + 2) * NPIX + n];
      float x3 = x[((size_t)b * CC + c0 + cs + 3) * NPIX + n];
#pragma unroll
      for (int j = 0; j < 18; ++j) {
        int o = og * 18 + j;
        const float4 w = *(const float4*)&wlds[o * 64 + cs];
        acc[j] = fmaf(x0, w.x, fmaf(x1, w.y, fmaf(x2, w.z, fmaf(x3, w.w, acc[j]))));
      }
    }
  }
#pragma unroll
  for (int j = 0; j < 18; ++j) {
    int o = og * 18 + j;
    if (o < 64)      q_pre[((size_t)b * 64 + o) * NPIX + n] = acc[j];
    else if (o < 80) k_pre[((size_t)b * 16 + (o - 64)) * NPIX + n] = acc[j];
    else             v_pre[((size_t)b * 64 + (o - 80)) * NPIX + n] = acc[j];
  }
}

// ---------------- K2a: BN batch stats -> scale/shift ----------------
__global__ __launch_bounds__(256) void k_bnstats(const float* __restrict__ q_pre,
    const float* __restrict__ v_pre,
    const float* __restrict__ bn_q_w, const float* __restrict__ bn_q_b,
    const float* __restrict__ bn_v_w, const float* __restrict__ bn_v_b,
    float* __restrict__ stats) {
  int ch = blockIdx.x;            // 0..127
  bool isq = ch < 64;
  int c = isq ? ch : ch - 64;
  const float* src = (isq ? q_pre : v_pre) + (size_t)c * NPIX;
  float s = 0.f, ss = 0.f;
  for (int idx = threadIdx.x; idx < BB * NPIX; idx += 256) {
    int bb = idx >> 10, nn = idx & 1023;
    float v = src[(size_t)bb * 64 * NPIX + nn];
    s += v; ss = fmaf(v, v, ss);
  }
#pragma unroll
  for (int off = 32; off > 0; off >>= 1) {
    s += __shfl_down(s, off);
    ss += __shfl_down(ss, off);
  }
  __shared__ float sh[8];
  if ((threadIdx.x & 63) == 0) {
    sh[(threadIdx.x >> 6) * 2] = s;
    sh[(threadIdx.x >> 6) * 2 + 1] = ss;
  }
  __syncthreads();
  if (threadIdx.x == 0) {
    s = sh[0] + sh[2] + sh[4] + sh[6];
    ss = sh[1] + sh[3] + sh[5] + sh[7];
    const float inv = 1.0f / (float)(BB * NPIX);
    float mean = s * inv;
    float var = ss * inv - mean * mean;
    float rstd = rsqrtf(var + EPSBN);
    float w = isq ? bn_q_w[c] : bn_v_w[c];
    float bi = isq ? bn_q_b[c] : bn_v_b[c];
    float scale = rstd * w;
    float shift = bi - mean * scale;
    if (isq) { stats[c] = scale; stats[64 + c] = shift; }
    else     { stats[128 + c] = scale; stats[192 + c] = shift; }
  }
}

// ---------------- K2c: normalize v in place + transposed copy ----------------
__global__ __launch_bounds__(256) void k_norm_v(float* __restrict__ vn,
    const float* __restrict__ stats, float* __restrict__ vnT) {
  __shared__ float lds[64 * 65];
  int b = blockIdx.y, n0 = blockIdx.x * 64;
  for (int l = threadIdx.x; l < 4096; l += 256) {
    int o = l >> 6, nn = l & 63;
    size_t a = ((size_t)b * 64 + o) * NPIX + n0 + nn;
    float v = fmaf(vn[a], stats[128 + o], stats[192 + o]);
    vn[a] = v;
    lds[o * 65 + nn] = v;
  }
  __syncthreads();
  for (int l = threadIdx.x; l < 4096; l += 256) {
    int nn = l >> 6, o = l & 63;
    vnT[((size_t)b * NPIX + n0 + nn) * 64 + o] = lds[o * 65 + nn];
  }
}

// ---------------- K3: softmax over N per (b,k) ----------------
__global__ __launch_bounds__(256) void k_softmax(const float* __restrict__ k_pre,
    float* __restrict__ p) {
  int b = blockIdx.y, k = blockIdx.x, t = threadIdx.x;
  const float* src = k_pre + ((size_t)b * 16 + k) * NPIX;
  float v[4];
  float mx = -1e30f;
#pragma unroll
  for (int i = 0; i < 4; ++i) { v[i] = src[t + 256 * i]; mx = fmaxf(mx, v[i]); }
#pragma unroll
  for (int off = 32; off > 0; off >>= 1) mx = fmaxf(mx, __shfl_down(mx, off));
  __shared__ float shm[4], shs[4];
  if ((t & 63) == 0) shm[t >> 6] = mx;
  __syncthreads();
  mx = fmaxf(fmaxf(shm[0], shm[1]), fmaxf(shm[2], shm[3]));
  float s = 0.f;
#pragma unroll
  for (int i = 0; i < 4; ++i) { v[i] = __expf(v[i] - mx); s += v[i]; }
#pragma unroll
  for (int off = 32; off > 0; off >>= 1) s += __shfl_down(s, off);
  if ((t & 63) == 0) shs[t >> 6] = s;
  __syncthreads();
  float r = 1.0f / (shs[0] + shs[1] + shs[2] + shs[3]);
  float* dst = p + ((size_t)b * 16 + k) * NPIX;
#pragma unroll
  for (int i = 0; i < 4; ++i) dst[t + 256 * i] = v[i] * r;
}

// ---------------- K4: lambda_c[b][k][v] ----------------
__global__ __launch_bounds__(256) void k_lambda_c(const float* __restrict__ p,
    const float* __restrict__ vnT, float* __restrict__ lc) {
  __shared__ float pl[1024];
  __shared__ float red[256];
  int b = blockIdx.y, k = blockIdx.x, t = threadIdx.x;
  const float* ps = p + ((size_t)b * 16 + k) * NPIX;
  for (int l = t; l < 1024; l += 256) pl[l] = ps[l];
  __syncthreads();
  int v = t & 63, nq = t >> 6;
  const float* vt = vnT + (size_t)b * NPIX * 64;
  float acc = 0.f;
  for (int n = nq * 256; n < nq * 256 + 256; ++n)
    acc = fmaf(pl[n], vt[(size_t)n * 64 + v], acc);
  red[t] = acc;
  __syncthreads();
  if (t < 64)
    lc[((size_t)b * 16 + k) * 64 + t] = red[t] + red[64 + t] + red[128 + t] + red[192 + t];
}

// ---------------- shared LDS layout for conv kernels ----------------
#define IMG_RS 68            // shorts per padded row
#define IMG_CS (54 * IMG_RS) // shorts per copy = 3672
#define LAM_RS 1032          // lambda row stride in shorts (1024 + 8 pad)

union KMainLDS {
  short imgc[4 * IMG_CS];   // 29376 B
  short lam[16 * LAM_RS];   // 33024 B
};

__device__ __forceinline__ short8v ld_win(const short* p) {
  union { short8v s8; short4v s4[2]; } bu;
  bu.s4[0] = *(const short4v*)p;
  bu.s4[1] = *(const short4v*)(p + 4);
  return bu.s8;
}

// ---------------- K5a: MFMA conv with rolling B-fragment register cache ------
// B-fragment identity: data for (tile tt, dr+1) == (tt+2, dr); cache 8 rows x
// 2 halves in registers (64 VGPR), load only 1 new image row per dr.
__global__ __launch_bounds__(256, 3) void k_conv(const float* __restrict__ vn,
    const float* __restrict__ lc, const unsigned short* __restrict__ embA,
    unsigned short* __restrict__ lamG) {
  __shared__ __align__(16) KMainLDS u;
  __shared__ float lcv[16];
  int b = blockIdx.y, v = blockIdx.x, t = threadIdx.x;

  int4* z4 = (int4*)u.imgc;
  for (int l = t; l < 1836; l += 256) z4[l] = make_int4(0, 0, 0, 0);
  if (t < 16) lcv[t] = lc[((size_t)b * 16 + t) * 64 + v];
  __syncthreads();

  const float* vsrc = vn + ((size_t)b * 64 + v) * NPIX;
  for (int l = t; l < 512; l += 256) {
    int pix = l * 2;
    int y = pix >> 5, xx = pix & 31;
    float2 vv = *(const float2*)(vsrc + pix);
    unsigned short h0 = f2bf(vv.x), h1 = f2bf(vv.y);
#pragma unroll
    for (int s = 0; s < 4; ++s) {
      int base = s * IMG_CS + (y + PADR) * IMG_RS + xx + PADR + s;
      u.imgc[base] = (short)h0;
      u.imgc[base + 1] = (short)h1;
    }
  }
  __syncthreads();

  int lane = t & 63, wv = t >> 6;
  int nl = lane & 15, quad = lane >> 4;
  int y0 = wv * 8;
  int scopy = (4 - (nl & 3)) & 3;
  int colbase = scopy * IMG_CS + nl + quad * 8 + scopy;
  const unsigned short* aptr = embA + nl * 32 + quad * 8;

  floatx4 acc[16];
#pragma unroll
  for (int i = 0; i < 16; ++i) acc[i] = (floatx4){0.f, 0.f, 0.f, 0.f};

  // prologue: cache rows y0..y0+7 (slot = row & 7)
  short8v bfrag[8][2];
#pragma unroll
  for (int rr = 0; rr < 8; ++rr) {
    const short* rp = &u.imgc[(y0 + rr) * IMG_RS + colbase];
    bfrag[rr][0] = ld_win(rp);
    bfrag[rr][1] = ld_win(rp + 16);
  }

  // depth-2 embA prefetch ring
  short8v a0 = *(const short8v*)aptr;
  short8v a1 = *(const short8v*)(aptr + 512);
#pragma unroll
  for (int dr = 0; dr < RR; ++dr) {
    short8v afrag = a0;
    a0 = a1;
    if (dr < RR - 2) a1 = *(const short8v*)(aptr + (dr + 2) * 512);
#pragma unroll
    for (int rr = 0; rr < 8; ++rr) {
      int slot = (dr + rr) & 7;
      acc[rr * 2 + 0] = __builtin_amdgcn_mfma_f32_16x16x32_bf16(afrag, bfrag[slot][0], acc[rr * 2 + 0], 0, 0, 0);
      acc[rr * 2 + 1] = __builtin_amdgcn_mfma_f32_16x16x32_bf16(afrag, bfrag[slot][1], acc[rr * 2 + 1], 0, 0, 0);
    }
    if (dr < RR - 1) {
      const short* rp = &u.imgc[(y0 + dr + 8) * IMG_RS + colbase];
      int slot = dr & 7;
      bfrag[slot][0] = ld_win(rp);
      bfrag[slot][1] = ld_win(rp + 16);
    }
  }

  __syncthreads();
#pragma unroll
  for (int tt = 0; tt < 16; ++tt) {
    int y = y0 + (tt >> 1), c0 = (tt & 1) << 4;
    int pix = y * 32 + c0 + nl;
#pragma unroll
    for (int r = 0; r < 4; ++r)
      u.lam[(quad * 4 + r) * LAM_RS + pix] = (short)f2bf(acc[tt][r] + lcv[quad * 4 + r]);
  }
  __syncthreads();

  // coalesced LDS -> global copy of lambda (16 rows x 1024 bf16 = 2048 uint4)
  uint4* dst = (uint4*)(lamG + ((size_t)(b * 64 + v)) * 16 * 1024);
  for (int idx = t; idx < 2048; idx += 256) {
    int row = idx >> 7, col = idx & 127;
    dst[row * 128 + col] = *(const uint4*)&u.lam[row * LAM_RS + col * 8];
  }
}

// ---------------- K5b: epilogue y = (1+g) * sum_k qn[k] * lambda[k] ----------
__global__ __launch_bounds__(256) void k_epi(const unsigned short* __restrict__ lamG,
    const float* __restrict__ q_pre, const float* __restrict__ stats,
    const float* __restrict__ gamma, float* __restrict__ out) {
  int b = blockIdx.y, v = blockIdx.x, t = threadIdx.x;
  int p0 = t * 4;
  const unsigned short* ls = lamG + ((size_t)(b * 64 + v)) * 16 * 1024;
  float yacc[4][4];
#pragma unroll
  for (int h = 0; h < 4; ++h)
#pragma unroll
    for (int i = 0; i < 4; ++i) yacc[h][i] = 0.f;
  const float* qb = q_pre + ((size_t)b * 64) * NPIX + p0;
#pragma unroll
  for (int k = 0; k < 16; ++k) {
    uint2 w = *(const uint2*)(ls + k * 1024 + p0);
    float l0 = bf2f((unsigned short)(w.x & 0xffffu));
    float l1 = bf2f((unsigned short)(w.x >> 16));
    float l2 = bf2f((unsigned short)(w.y & 0xffffu));
    float l3 = bf2f((unsigned short)(w.y >> 16));
#pragma unroll
    for (int h = 0; h < 4; ++h) {
      int o = h * 16 + k;
      float4 qv = *(const float4*)(qb + (size_t)o * NPIX);
      float s = stats[o], sh = stats[64 + o];
      yacc[h][0] = fmaf(fmaf(qv.x, s, sh), l0, yacc[h][0]);
      yacc[h][1] = fmaf(fmaf(qv.y, s, sh), l1, yacc[h][1]);
      yacc[h][2] = fmaf(fmaf(qv.z, s, sh), l2, yacc[h][2]);
      yacc[h][3] = fmaf(fmaf(qv.w, s, sh), l3, yacc[h][3]);
    }
  }
  float g1 = 1.0f + gamma[0];
#pragma unroll
  for (int h = 0; h < 4; ++h) {
    float4 r;
    r.x = g1 * yacc[h][0]; r.y = g1 * yacc[h][1];
    r.z = g1 * yacc[h][2]; r.w = g1 * yacc[h][3];
    *(float4*)&out[((size_t)b * 256 + h * 64 + v) * NPIX + p0] = r;
  }
}

// ---------------- K5 fallback: R4 fused k_main (verbatim, known-passing) -----
__global__ __launch_bounds__(256) void k_main(const float* __restrict__ vn,
    const float* __restrict__ q_pre, const float* __restrict__ stats,
    const float* __restrict__ lc, const unsigned short* __restrict__ embA,
    const float* __restrict__ gamma, float* __restrict__ out) {
  __shared__ __align__(16) KMainLDS u;
  __shared__ float lcv[16];
  int b = blockIdx.y, v = blockIdx.x, t = threadIdx.x;

  int4* z4 = (int4*)u.imgc;
  for (int l = t; l < 1836; l += 256) z4[l] = make_int4(0, 0, 0, 0);
  if (t < 16) lcv[t] = lc[((size_t)b * 16 + t) * 64 + v];
  __syncthreads();

  const float* vsrc = vn + ((size_t)b * 64 + v) * NPIX;
  for (int l = t; l < 512; l += 256) {
    int pix = l * 2;
    int y = pix >> 5, xx = pix & 31;
    float2 vv = *(const float2*)(vsrc + pix);
    unsigned short h0 = f2bf(vv.x), h1 = f2bf(vv.y);
#pragma unroll
    for (int s = 0; s < 4; ++s) {
      int base = s * IMG_CS + (y + PADR) * IMG_RS + xx + PADR + s;
      u.imgc[base] = (short)h0;
      u.imgc[base + 1] = (short)h1;
    }
  }
  __syncthreads();

  int lane = t & 63, wv = t >> 6;
  int nl = lane & 15, quad = lane >> 4;
  int y0 = wv * 8;
  int scopy = (4 - (nl & 3)) & 3;
  int colbase = scopy * IMG_CS + nl + quad * 8 + scopy;
  const unsigned short* aptr = embA + nl * 32 + quad * 8;

  floatx4 acc[16];
#pragma unroll
  for (int i = 0; i < 16; ++i) acc[i] = (floatx4){0.f, 0.f, 0.f, 0.f};

  short8v afrag = *(const short8v*)aptr;
  for (int dr = 0; dr < RR; ++dr) {
    short8v anext = afrag;
    if (dr < RR - 1) anext = *(const short8v*)(aptr + (dr + 1) * 512);
    int rowoff = (y0 + dr) * IMG_RS + colbase;
#pragma unroll
    for (int tt = 0; tt < 16; ++tt) {
      int addr = rowoff + (tt >> 1) * IMG_RS + ((tt & 1) << 4);
      union { short8v s8; short4v s4[2]; } bu;
      bu.s4[0] = *(const short4v*)&u.imgc[addr];
      bu.s4[1] = *(const short4v*)&u.imgc[addr + 4];
      acc[tt] = __builtin_amdgcn_mfma_f32_16x16x32_bf16(afrag, bu.s8, acc[tt], 0, 0, 0);
    }
    afrag = anext;
  }

  __syncthreads();
#pragma unroll
  for (int tt = 0; tt < 16; ++tt) {
    int y = y0 + (tt >> 1), c0 = (tt & 1) << 4;
    int pix = y * 32 + c0 + nl;
#pragma unroll
    for (int r = 0; r < 4; ++r)
      u.lam[(quad * 4 + r) * LAM_RS + pix] = (short)f2bf(acc[tt][r] + lcv[quad * 4 + r]);
  }
  __syncthreads();

  int p0 = t * 4;
  float yacc[4][4];
#pragma unroll
  for (int h = 0; h < 4; ++h)
#pragma unroll
    for (int i = 0; i < 4; ++i) yacc[h][i] = 0.f;
  const float* qb = q_pre + ((size_t)b * 64) * NPIX + p0;
#pragma unroll
  for (int k = 0; k < 16; ++k) {
    uint2 w = *(const uint2*)&u.lam[k * LAM_RS + p0];
    float l0 = bf2f((unsigned short)(w.x & 0xffffu));
    float l1 = bf2f((unsigned short)(w.x >> 16));
    float l2 = bf2f((unsigned short)(w.y & 0xffffu));
    float l3 = bf2f((unsigned short)(w.y >> 16));
#pragma unroll
    for (int h = 0; h < 4; ++h) {
      int o = h * 16 + k;
      float4 qv = *(const float4*)(qb + (size_t)o * NPIX);
      float s = stats[o], sh = stats[64 + o];
      yacc[h][0] = fmaf(fmaf(qv.x, s, sh), l0, yacc[h][0]);
      yacc[h][1] = fmaf(fmaf(qv.y, s, sh), l1, yacc[h][1]);
      yacc[h][2] = fmaf(fmaf(qv.z, s, sh), l2, yacc[h][2]);
      yacc[h][3] = fmaf(fmaf(qv.w, s, sh), l3, yacc[h][3]);
    }
  }
  float g1 = 1.0f + gamma[0];
#pragma unroll
  for (int h = 0; h < 4; ++h) {
    float4 r;
    r.x = g1 * yacc[h][0]; r.y = g1 * yacc[h][1];
    r.z = g1 * yacc[h][2]; r.w = g1 * yacc[h][3];
    *(float4*)&out[((size_t)b * 256 + h * 64 + v) * NPIX + p0] = r;
  }
}

extern "C" void kernel_launch(void* const* d_in, const int* in_sizes, int n_in,
                              void* d_out, int out_size, void* d_ws, size_t ws_size,
                              hipStream_t stream) {
  const float* x      = (const float*)d_in[0];
  const float* Wq     = (const float*)d_in[1];
  const float* bn_q_w = (const float*)d_in[2];
  const float* bn_q_b = (const float*)d_in[3];
  const float* Wk     = (const float*)d_in[4];
  const float* Wv     = (const float*)d_in[5];
  const float* bn_v_w = (const float*)d_in[6];
  const float* bn_v_b = (const float*)d_in[7];
  const float* emb    = (const float*)d_in[8];
  const float* gamma  = (const float*)d_in[9];
  float* out = (float*)d_out;

  float* ws    = (float*)d_ws;
  float* q_pre = ws;                                     // B*64*N
  float* k_pre = q_pre + (size_t)BB * 64 * NPIX;         // B*16*N
  float* vn    = k_pre + (size_t)BB * 16 * NPIX;         // B*64*N
  float* vnT   = vn    + (size_t)BB * 64 * NPIX;         // B*N*64
  float* p     = vnT   + (size_t)BB * NPIX * 64;         // B*16*N
  float* lc    = p     + (size_t)BB * 16 * NPIX;         // B*16*64
  float* stats = lc    + (size_t)BB * 16 * 64;           // 256
  unsigned short* embA = (unsigned short*)(stats + 256); // 23*16*32 ushorts
  unsigned short* lamG = embA + 23 * 16 * 32;            // B*64*16*N ushorts (64 MB)

  size_t need = ((size_t)(lamG - (unsigned short*)ws)) * 2
              + (size_t)BB * 64 * 16 * NPIX * 2;

  k_emb     <<<dim3(46),     256, 0, stream>>>(emb, embA);
  k_proj    <<<dim3(32, BB), 256, 0, stream>>>(x, Wq, Wk, Wv, q_pre, k_pre, vn);
  k_bnstats <<<dim3(128),    256, 0, stream>>>(q_pre, vn, bn_q_w, bn_q_b, bn_v_w, bn_v_b, stats);
  k_norm_v  <<<dim3(16, BB), 256, 0, stream>>>(vn, stats, vnT);
  k_softmax <<<dim3(16, BB), 256, 0, stream>>>(k_pre, p);
  k_lambda_c<<<dim3(16, BB), 256, 0, stream>>>(p, vnT, lc);
  if (ws_size >= need) {
    k_conv  <<<dim3(64, BB), 256, 0, stream>>>(vn, lc, embA, lamG);
    k_epi   <<<dim3(64, BB), 256, 0, stream>>>(lamG, q_pre, stats, gamma, out);
  } else {
    k_main  <<<dim3(64, BB), 256, 0, stream>>>(vn, q_pre, stats, lc, embA, gamma, out);
  }
}